// Round 2
// baseline (206.045 us; speedup 1.0000x reference)
//
#include <hip/hip_runtime.h>

// GIoU loss, 3D boxes, matched pairs, sum-reduced and negated.
// Box row layout: [x1, y1, x2, y2, z1, z2] (6 f32, 24 B -> pair of boxes = 48 B = 3 float4).
//
// R1 diagnosis: direct AoS float4 loads have 48B lane stride (3x cacheline
// transactions per VMEM instr) and the compiler allocated only 28 VGPRs so
// loads serialized -> latency-bound at 2.7 TB/s. Fix: stage tiles via
// __builtin_amdgcn_global_load_lds (coalesced, zero-VGPR, async), consume
// from LDS via ds_read_b128.

namespace {

constexpr float kEps     = 1e-7f;
constexpr int   kThreads = 256;              // multiple of wave=64
constexpr int   kTilePairs = 256;            // one pair per thread per tile
constexpr int   kF4PerArr  = kTilePairs * 3; // 768 float4 = 12 KiB per array
constexpr int   kBlocks    = 2048;           // grid-stride over tiles

__device__ __forceinline__ float giou1(
    float px1, float py1, float px2, float py2, float pz1, float pz2,
    float tx1, float ty1, float tx2, float ty2, float tz1, float tz2)
{
    float vol1 = (px2 - px1) * (py2 - py1) * (pz2 - pz1);
    float vol2 = (tx2 - tx1) * (ty2 - ty1) * (tz2 - tz1);

    float ix = fmaxf(fminf(px2, tx2) - fmaxf(px1, tx1), 0.0f);
    float iy = fmaxf(fminf(py2, ty2) - fmaxf(py1, ty1), 0.0f);
    float iz = fmaxf(fminf(pz2, tz2) - fmaxf(pz1, tz1), 0.0f);
    float inter = ix * iy * iz;
    float uni = vol1 + vol2 - inter;
    float iou = inter / uni;

    float ex = fmaxf(fmaxf(px2, tx2) - fminf(px1, tx1), 0.0f);
    float ey = fmaxf(fmaxf(py2, ty2) - fminf(py1, ty1), 0.0f);
    float ez = fmaxf(fmaxf(pz2, tz2) - fminf(pz1, tz1), 0.0f);
    float enc = ex * ey * ez + kEps;

    return iou - (enc - uni) / enc;
}

// Async global->LDS, 16B per lane. LDS dest must be wave-uniform base;
// HW adds lane*16. Global src is per-lane.
__device__ __forceinline__ void stage16(const float4* gsrc, float4* ldst) {
    __builtin_amdgcn_global_load_lds(
        (const __attribute__((address_space(1))) void*)gsrc,
        (__attribute__((address_space(3))) void*)ldst,
        16 /*bytes, literal*/, 0 /*offset*/, 0 /*aux*/);
}

__global__ __launch_bounds__(kThreads) void giou_partial_kernel(
    const float* __restrict__ pred, const float* __restrict__ targ,
    double* __restrict__ partials, int npairs)
{
    __shared__ float4 ldsP[kF4PerArr];   // 12 KiB
    __shared__ float4 ldsT[kF4PerArr];   // 12 KiB  (24 KiB total -> 6 blocks/CU)

    const float4* __restrict__ p4 = reinterpret_cast<const float4*>(pred);
    const float4* __restrict__ t4 = reinterpret_cast<const float4*>(targ);

    const int tid    = threadIdx.x;
    const int wbase  = tid & ~63;                 // wave-uniform chunk base
    const int ntiles = (npairs + kTilePairs - 1) / kTilePairs;

    double acc = 0.0;

    for (int tile = blockIdx.x; tile < ntiles; tile += gridDim.x) {
        const int pair0 = tile * kTilePairs;
        if (pair0 + kTilePairs <= npairs) {
            // ---- fast path: fully coalesced async staging ----
            const size_t f4base = (size_t)pair0 * 3;
            #pragma unroll
            for (int c = 0; c < 3; ++c) {
                const int idx = c * kThreads + tid;             // per-lane
                const int lbase = c * kThreads + wbase;         // wave-uniform
                stage16(p4 + f4base + idx, ldsP + lbase);
                stage16(t4 + f4base + idx, ldsT + lbase);
            }
            __syncthreads();   // compiler drains vmcnt before s_barrier

            // pair tid: 3 x ds_read_b128 per array at 48B stride (~2-way, free)
            float4 pa = ldsP[3 * tid + 0];
            float4 pb = ldsP[3 * tid + 1];
            float4 pc = ldsP[3 * tid + 2];
            float4 ta = ldsT[3 * tid + 0];
            float4 tb = ldsT[3 * tid + 1];
            float4 tc = ldsT[3 * tid + 2];

            // box 2i  : x1=a.x y1=a.y x2=a.z y2=a.w z1=b.x z2=b.y
            // box 2i+1: x1=b.z y1=b.w x2=c.x y2=c.y z1=c.z z2=c.w
            float g0 = giou1(pa.x, pa.y, pa.z, pa.w, pb.x, pb.y,
                             ta.x, ta.y, ta.z, ta.w, tb.x, tb.y);
            float g1 = giou1(pb.z, pb.w, pc.x, pc.y, pc.z, pc.w,
                             tb.z, tb.w, tc.x, tc.y, tc.z, tc.w);
            acc += (double)g0 + (double)g1;

            __syncthreads();   // protect LDS before next tile overwrites
        } else {
            // ---- tail tile (at most one block reaches here) ----
            const int i = pair0 + tid;
            if (i < npairs) {
                const size_t b = 3 * (size_t)i;
                float4 pa = p4[b + 0], pb = p4[b + 1], pc = p4[b + 2];
                float4 ta = t4[b + 0], tb = t4[b + 1], tc = t4[b + 2];
                float g0 = giou1(pa.x, pa.y, pa.z, pa.w, pb.x, pb.y,
                                 ta.x, ta.y, ta.z, ta.w, tb.x, tb.y);
                float g1 = giou1(pb.z, pb.w, pc.x, pc.y, pc.z, pc.w,
                                 tb.z, tb.w, tc.x, tc.y, tc.z, tc.w);
                acc += (double)g0 + (double)g1;
            }
        }
    }

    // Wave (64-lane) reduce, then cross-wave via LDS.
    #pragma unroll
    for (int off = 32; off > 0; off >>= 1)
        acc += __shfl_down(acc, off, 64);

    __shared__ double smem[kThreads / 64];
    const int lane = tid & 63;
    const int wid  = tid >> 6;
    if (lane == 0) smem[wid] = acc;
    __syncthreads();
    if (tid == 0) {
        double s = 0.0;
        #pragma unroll
        for (int w = 0; w < kThreads / 64; ++w) s += smem[w];
        partials[blockIdx.x] = s;   // unconditional: every block writes its slot
    }
}

__global__ __launch_bounds__(kThreads) void giou_final_kernel(
    const double* __restrict__ partials, int n,
    const float* __restrict__ pred, const float* __restrict__ targ, int nboxes,
    float* __restrict__ out)
{
    double acc = 0.0;
    for (int i = threadIdx.x; i < n; i += kThreads) acc += partials[i];

    #pragma unroll
    for (int off = 32; off > 0; off >>= 1)
        acc += __shfl_down(acc, off, 64);

    __shared__ double smem[kThreads / 64];
    const int lane = threadIdx.x & 63;
    const int wid  = threadIdx.x >> 6;
    if (lane == 0) smem[wid] = acc;
    __syncthreads();
    if (threadIdx.x == 0) {
        double s = 0.0;
        #pragma unroll
        for (int w = 0; w < kThreads / 64; ++w) s += smem[w];
        if (nboxes & 1) {   // defensive odd-box tail (dead for N=4e6)
            const float* pp = pred + (size_t)(nboxes - 1) * 6;
            const float* tt = targ + (size_t)(nboxes - 1) * 6;
            s += (double)giou1(pp[0], pp[1], pp[2], pp[3], pp[4], pp[5],
                               tt[0], tt[1], tt[2], tt[3], tt[4], tt[5]);
        }
        out[0] = (float)(-1.0 * s);   // LOSS_WEIGHT * -1 * sum
    }
}

}  // namespace

extern "C" void kernel_launch(void* const* d_in, const int* in_sizes, int n_in,
                              void* d_out, int out_size, void* d_ws, size_t ws_size,
                              hipStream_t stream) {
    const float* pred = (const float*)d_in[0];
    const float* targ = (const float*)d_in[1];
    float* out = (float*)d_out;

    const int nboxes = in_sizes[0] / 6;    // 4,000,000
    const int npairs = nboxes / 2;         // 2,000,000

    double* partials = (double*)d_ws;      // kBlocks * 8 B = 16 KiB << ws_size

    giou_partial_kernel<<<kBlocks, kThreads, 0, stream>>>(
        pred, targ, partials, npairs);
    giou_final_kernel<<<1, kThreads, 0, stream>>>(
        partials, kBlocks, pred, targ, nboxes, out);
}